// Round 2
// baseline (527.153 us; speedup 1.0000x reference)
//
#include <hip/hip_runtime.h>
#include <math.h>

// Round 1: identical to Round 0 submission — the bench failed with a
// container-acquisition infra error ("MI355X container failed twice"),
// so no measurement was taken. Resubmitting to get data.

#define EMB_D 768
#define SEQ_S 512
#define BLOCK 1024
#define NWAVES (BLOCK / 64)            // 16 waves
#define ROWS_PER_WAVE (SEQ_S / NWAVES) // 32 rows per wave
#define RB 8                           // rows per batched reduction

// One block per batch element. Phase 1: each wave computes, for batches of
// RB=8 of its rows, score[s] = emb[b,s,:]·w_att and t[s] = emb[b,s,:]·w_pred
// in a single pass (single HBM read of embeddings). Loads for 8 rows are
// issued in two 12-load groups (high MLP); the 64-lane reduction is done
// jointly for all 8 rows via a select+shfl_xor multiplexed butterfly:
// after rounds off=1,2,4 lane L holds the 8-lane-group sum of row (L&7);
// rounds 8,16,32 complete the wave sum. 20 shfls per 8 rows vs 96 before.
// Phase 2: block softmax over score[0..511], weighted sum of t, sigmoid.
__global__ __launch_bounds__(BLOCK, 1) void attn_pool_kernel(
    const float* __restrict__ emb,     // [B, S, D]
    const float* __restrict__ w_att,   // [D]
    const float* __restrict__ w_pred,  // [D]
    const float* __restrict__ b_pred,  // [1]
    float* __restrict__ out)           // [B]
{
    __shared__ float s_score[SEQ_S];
    __shared__ float s_t[SEQ_S];
    __shared__ float s_red_a[NWAVES];
    __shared__ float s_red_b[NWAVES];

    const int b    = blockIdx.x;
    const int tid  = threadIdx.x;
    const int lane = tid & 63;
    const int wave = tid >> 6;

    // Weight fragments in registers: lane covers float4 indices lane, lane+64, lane+128
    const float4* wa4 = (const float4*)w_att;
    const float4* wp4 = (const float4*)w_pred;
    float4 wa[3], wp[3];
#pragma unroll
    for (int c = 0; c < 3; ++c) {
        wa[c] = wa4[lane + 64 * c];
        wp[c] = wp4[lane + 64 * c];
    }

    const float4* e4 = (const float4*)(emb + (size_t)b * SEQ_S * EMB_D);

    const bool s0b = (lane & 1) != 0;
    const bool s1b = (lane & 2) != 0;
    const bool s2b = (lane & 4) != 0;

    // ---- Phase 1: batched dual dot products ----
#pragma unroll 1
    for (int base = 0; base < ROWS_PER_WAVE; base += RB) {
        const int s0 = wave * ROWS_PER_WAVE + base;
        const float4* rp = e4 + (size_t)s0 * (EMB_D / 4) + lane;

        float sa[RB], sp[RB];
#pragma unroll
        for (int r = 0; r < RB; ++r) { sa[r] = 0.f; sp[r] = 0.f; }

        // Two halves of 4 rows; each half stages all 12 float4 loads (high MLP),
        // all indices compile-time constant (no scratch spill).
#pragma unroll
        for (int h = 0; h < 2; ++h) {
            float4 v[4][3];
#pragma unroll
            for (int r = 0; r < 4; ++r)
#pragma unroll
                for (int c = 0; c < 3; ++c)
                    v[r][c] = rp[(h * 4 + r) * (EMB_D / 4) + 64 * c];
#pragma unroll
            for (int r = 0; r < 4; ++r) {
#pragma unroll
                for (int c = 0; c < 3; ++c) {
                    const int rr = h * 4 + r;
                    sa[rr] = fmaf(v[r][c].x, wa[c].x, sa[rr]);
                    sa[rr] = fmaf(v[r][c].y, wa[c].y, sa[rr]);
                    sa[rr] = fmaf(v[r][c].z, wa[c].z, sa[rr]);
                    sa[rr] = fmaf(v[r][c].w, wa[c].w, sa[rr]);
                    sp[rr] = fmaf(v[r][c].x, wp[c].x, sp[rr]);
                    sp[rr] = fmaf(v[r][c].y, wp[c].y, sp[rr]);
                    sp[rr] = fmaf(v[r][c].z, wp[c].z, sp[rr]);
                    sp[rr] = fmaf(v[r][c].w, wp[c].w, sp[rr]);
                }
            }
        }

        // ---- multiplexed 8-row reduction ----
        // Round off=1: pair rows (2j, 2j+1); select by lane bit0.
        float ua[4], up[4];
#pragma unroll
        for (int j = 0; j < 4; ++j) {
            ua[j] = (s0b ? sa[2*j+1] : sa[2*j])
                  + __shfl_xor(s0b ? sa[2*j] : sa[2*j+1], 1, 64);
            up[j] = (s0b ? sp[2*j+1] : sp[2*j])
                  + __shfl_xor(s0b ? sp[2*j] : sp[2*j+1], 1, 64);
        }
        // Round off=2: select by lane bit1.
        float pa[2], pq[2];
#pragma unroll
        for (int j = 0; j < 2; ++j) {
            pa[j] = (s1b ? ua[2*j+1] : ua[2*j])
                  + __shfl_xor(s1b ? ua[2*j] : ua[2*j+1], 2, 64);
            pq[j] = (s1b ? up[2*j+1] : up[2*j])
                  + __shfl_xor(s1b ? up[2*j] : up[2*j+1], 2, 64);
        }
        // Round off=4: select by lane bit2. Now lane L holds 8-lane-group
        // partial of row (L&7).
        float ra = (s2b ? pa[1] : pa[0]) + __shfl_xor(s2b ? pa[0] : pa[1], 4, 64);
        float rt = (s2b ? pq[1] : pq[0]) + __shfl_xor(s2b ? pq[0] : pq[1], 4, 64);
        // Butterflies across the eight 8-lane groups.
#pragma unroll
        for (int off = 8; off < 64; off <<= 1) {
            ra += __shfl_xor(ra, off, 64);
            rt += __shfl_xor(rt, off, 64);
        }
        if (lane < RB) {
            s_score[s0 + lane] = ra;
            s_t[s0 + lane]     = rt;
        }
    }
    __syncthreads();

    // ---- Phase 2: softmax + weighted sum ----
    float score = -INFINITY, tval = 0.f;
    if (tid < SEQ_S) {
        score = s_score[tid];
        tval  = s_t[tid];
    }

    // block max
    float m = score;
#pragma unroll
    for (int off = 1; off < 64; off <<= 1)
        m = fmaxf(m, __shfl_xor(m, off, 64));
    if (lane == 0) s_red_a[wave] = m;
    __syncthreads();
    if (tid == 0) {
        float mm = s_red_a[0];
#pragma unroll
        for (int w = 1; w < NWAVES; ++w) mm = fmaxf(mm, s_red_a[w]);
        s_red_a[0] = mm;
    }
    __syncthreads();
    m = s_red_a[0];
    __syncthreads();   // protect s_red_a before reuse

    float e = (tid < SEQ_S) ? __expf(score - m) : 0.f;
    float se  = e;
    float set = e * tval;
#pragma unroll
    for (int off = 1; off < 64; off <<= 1) {
        se  += __shfl_xor(se, off, 64);
        set += __shfl_xor(set, off, 64);
    }
    if (lane == 0) {
        s_red_a[wave] = se;
        s_red_b[wave] = set;
    }
    __syncthreads();
    if (tid == 0) {
        float Z = 0.f, ET = 0.f;
#pragma unroll
        for (int w = 0; w < NWAVES; ++w) {
            Z  += s_red_a[w];
            ET += s_red_b[w];
        }
        float logit = ET / Z + b_pred[0];
        out[b] = 1.0f / (1.0f + __expf(-logit));
    }
}

extern "C" void kernel_launch(void* const* d_in, const int* in_sizes, int n_in,
                              void* d_out, int out_size, void* d_ws, size_t ws_size,
                              hipStream_t stream) {
    const float* emb    = (const float*)d_in[0]; // [256,512,768]
    const float* w_att  = (const float*)d_in[1]; // [768]
    const float* w_pred = (const float*)d_in[2]; // [768]
    const float* b_pred = (const float*)d_in[3]; // [1]
    float* out = (float*)d_out;                  // [256]

    const int B = in_sizes[0] / (SEQ_S * EMB_D); // 256
    attn_pool_kernel<<<B, BLOCK, 0, stream>>>(emb, w_att, w_pred, b_pred, out);
}